// Round 10
// baseline (255.029 us; speedup 1.0000x reference)
//
#include <hip/hip_runtime.h>

// Net_18966575579675: 722 tiny MLPs (11->10->10->6), B=8192, fp32.
// R14 = R13 resubmitted (container acquire failed twice — third instance
// of this infra signature; R8->R9 and R10->R11 both passed unchanged on
// resubmit; audit again found no hang/OOB/race). Theory unchanged:
// R4-R12 falsified grid, LDS size, barrier semantics, spills, occupancy
// (2x), weight fetch path, store-run length (R12: WRITE 225->140MB=ideal,
// dur flat) — all ~115-131us. Remaining invariant: every weight
// register-load fed only 2 rows of FMAs, so waves alternate short FMA
// bursts with load waits ~91x/phase (R7 had 4-row reuse but paid OoO-SMEM
// drains; R10/12 had pipelined LDS loads but 2-row reuse — never both).
// Fix: one phase per chunk, each lane computes 4 rows (lane, 64+l, 128+l,
// 192+l): LOAD10 feeds 4 independent FMA chains (2x fewer ds ops/FMA,
// 4-deep ILP, half the phases+barriers); camera (4 slots) lives in VGPRs
// for the whole block. obuf per-chunk 256x25 (25.6KB) + wbuf 23.5KB =
// 48KB exactly -> 3 blocks/CU. Flush = 96-B runs (R12 proved the write
// path has headroom; WRITE_SIZE is the tripwire if it becomes binding).

#define NN 722
#define CAMD 10
#define HD 10
#define LODD 6
#define ROWF (NN * LODD)       // 4332 floats per output row
#define NG 46                  // 45 full 4-chunk groups + 1 tail (1 chunk)
#define LSTRIDE 25             // obuf: 24 cols + 1 pad

// per-net LDS weight slot (floats), rows padded for 16B alignment:
//  w1: 11 x 12 @ 0    w2: 10 x 12 @ 132   w3: 10 x 8 @ 252
//  b1: 10 @ 332       b2: 10 @ 344        b3: 6 @ 356
#define NETSTRIDE 368
#define OFF_W2 132
#define OFF_W3 252
#define OFF_B1 332
#define OFF_B2 344
#define OFF_B3 356

// LDS-only barrier: order ds ops across waves WITHOUT draining vmcnt
// (global stores / prefetch loads stay in flight).
__device__ __forceinline__ void lds_barrier() {
    asm volatile("s_waitcnt lgkmcnt(0)" ::: "memory");
    __builtin_amdgcn_s_barrier();
}

// 10 consecutive LDS floats (base 16B-aligned)
#define LOAD10(dst, base) do {                                   \
    const float4 _a = *(const float4*)(base);                    \
    const float4 _b = *(const float4*)((base) + 4);              \
    const float2 _c = *(const float2*)((base) + 8);              \
    dst[0]=_a.x; dst[1]=_a.y; dst[2]=_a.z; dst[3]=_a.w;          \
    dst[4]=_b.x; dst[5]=_b.y; dst[6]=_b.z; dst[7]=_b.w;          \
    dst[8]=_c.x; dst[9]=_c.y; } while (0)

// 6 consecutive LDS floats (base 16B-aligned)
#define LOAD6(dst, base) do {                                    \
    const float4 _a = *(const float4*)(base);                    \
    const float2 _c = *(const float2*)((base) + 4);              \
    dst[0]=_a.x; dst[1]=_a.y; dst[2]=_a.z; dst[3]=_a.w;          \
    dst[4]=_c.x; dst[5]=_c.y; } while (0)

__global__ __launch_bounds__(256) void Net_18966575579675_kernel(
    const float* __restrict__ prior, const float* __restrict__ camera,
    const float* __restrict__ W1, const float* __restrict__ b1,
    const float* __restrict__ W2, const float* __restrict__ b2,
    const float* __restrict__ W3, const float* __restrict__ b3,
    float* __restrict__ out)
{
    const int tid  = threadIdx.x;
    const int lane = tid & 63;
    const int wave = __builtin_amdgcn_readfirstlane(tid >> 6);
    const int b0   = blockIdx.x * 256;
    const int g    = blockIdx.y;
    const int cig  = (g == NG - 1) ? 1 : 4;      // chunks in this group

    __shared__ __align__(16) float wbuf[16 * NETSTRIDE];  // 23552 B
    __shared__ float obuf[256 * LSTRIDE];                 // 25600 B -> 48K total

    // ---- stage this group's weights ONCE (wave-private slots: each wave
    // stages and reads only its own nets -> no barrier, in-order LDS) ----
#pragma unroll
    for (int c = 0; c < 4; ++c) {
        if (c < cig) {
            const int ns = g * 16 + c * 4 + wave;
            if (ns < NN) {
                float* wd = wbuf + (c * 4 + wave) * NETSTRIDE;
                const float* s1 = W1 + (size_t)ns * (CAMD + 1) * HD;   // 110
#pragma unroll
                for (int t0 = 0; t0 < 110; t0 += 64) {
                    const int t = t0 + lane;
                    if (t < 110) { const int i = t / 10, j = t - 10 * i; wd[i * 12 + j] = s1[t]; }
                }
                const float* s2 = W2 + (size_t)ns * HD * HD;           // 100
#pragma unroll
                for (int t0 = 0; t0 < 100; t0 += 64) {
                    const int t = t0 + lane;
                    if (t < 100) { const int j = t / 10, k = t - 10 * j; wd[OFF_W2 + j * 12 + k] = s2[t]; }
                }
                const float* s3 = W3 + (size_t)ns * HD * LODD;         // 60
                if (lane < 60) { const int j = lane / 6, m = lane - 6 * j; wd[OFF_W3 + j * 8 + m] = s3[lane]; }
                if (lane < 10)      wd[OFF_B1 + lane]      = b1[(size_t)ns * HD + lane];
                else if (lane < 20) wd[OFF_B2 + lane - 10] = b2[(size_t)ns * HD + lane - 10];
                else if (lane < 26) wd[OFF_B3 + lane - 20] = b3[(size_t)ns * LODD + lane - 20];
            }
        }
    }

    // ---- camera for all 4 row-slots -> registers, once per block ----
    float cam[4][CAMD];
#pragma unroll
    for (int s = 0; s < 4; ++s) {
        const float2* c2 = (const float2*)(camera + (size_t)(b0 + s * 64 + lane) * CAMD);
#pragma unroll
        for (int i = 0; i < CAMD / 2; ++i) {
            const float2 v = c2[i];
            cam[s][2 * i]     = v.x;
            cam[s][2 * i + 1] = v.y;
        }
    }

    // ---- prior prefetch for chunk 0 (clamped; clamped lanes unused) ----
    float pr[4];
    {
        const int n0 = g * 16 + wave;
        const int nc = n0 < NN ? n0 : NN - 1;
#pragma unroll
        for (int s = 0; s < 4; ++s)
            pr[s] = prior[(size_t)(b0 + s * 64 + lane) * NN + nc];
    }

#pragma unroll 1
    for (int c = 0; c < cig; ++c) {
        const int n   = g * 16 + c * 4 + wave;   // wave-uniform
        const bool act = (n < NN);

        // prefetch next chunk's prior (stores/loads never drained below)
        float prn[4];
#pragma unroll
        for (int s = 0; s < 4; ++s) prn[s] = pr[s];
        if (c + 1 < cig) {
            const int n1 = g * 16 + (c + 1) * 4 + wave;
            const int nc = n1 < NN ? n1 : NN - 1;
#pragma unroll
            for (int s = 0; s < 4; ++s)
                prn[s] = prior[(size_t)(b0 + s * 64 + lane) * NN + nc];
        }

        if (act) {
            const float* wb = wbuf + (c * 4 + wave) * NETSTRIDE;

            // ---- layer 1: 4 rows per weight load ----
            float h1[4][HD];
            {
                float bv[10]; LOAD10(bv, wb + OFF_B1);
                float wv[10]; LOAD10(wv, wb);          // W1 row 0 (prior)
#pragma unroll
                for (int j = 0; j < HD; ++j) {
                    h1[0][j] = fmaf(pr[0], wv[j], bv[j]);
                    h1[1][j] = fmaf(pr[1], wv[j], bv[j]);
                    h1[2][j] = fmaf(pr[2], wv[j], bv[j]);
                    h1[3][j] = fmaf(pr[3], wv[j], bv[j]);
                }
            }
#pragma unroll
            for (int i = 0; i < CAMD; ++i) {
                float wv[10]; LOAD10(wv, wb + (i + 1) * 12);
#pragma unroll
                for (int j = 0; j < HD; ++j) {
                    h1[0][j] = fmaf(cam[0][i], wv[j], h1[0][j]);
                    h1[1][j] = fmaf(cam[1][i], wv[j], h1[1][j]);
                    h1[2][j] = fmaf(cam[2][i], wv[j], h1[2][j]);
                    h1[3][j] = fmaf(cam[3][i], wv[j], h1[3][j]);
                }
            }
#pragma unroll
            for (int s = 0; s < 4; ++s)
#pragma unroll
                for (int j = 0; j < HD; ++j)
                    h1[s][j] = fmaxf(h1[s][j], 0.0f);

            // ---- layer 2 ----
            float h2[4][HD];
            {
                float bv[10]; LOAD10(bv, wb + OFF_B2);
#pragma unroll
                for (int k = 0; k < HD; ++k) {
                    h2[0][k] = bv[k]; h2[1][k] = bv[k];
                    h2[2][k] = bv[k]; h2[3][k] = bv[k];
                }
            }
#pragma unroll
            for (int j = 0; j < HD; ++j) {
                float wv[10]; LOAD10(wv, wb + OFF_W2 + j * 12);
#pragma unroll
                for (int k = 0; k < HD; ++k) {
                    h2[0][k] = fmaf(h1[0][j], wv[k], h2[0][k]);
                    h2[1][k] = fmaf(h1[1][j], wv[k], h2[1][k]);
                    h2[2][k] = fmaf(h1[2][j], wv[k], h2[2][k]);
                    h2[3][k] = fmaf(h1[3][j], wv[k], h2[3][k]);
                }
            }
#pragma unroll
            for (int s = 0; s < 4; ++s)
#pragma unroll
                for (int k = 0; k < HD; ++k)
                    h2[s][k] = fmaxf(h2[s][k], 0.0f);

            // ---- layer 3 + stash ----
            float o[4][LODD];
            {
                float bv[6]; LOAD6(bv, wb + OFF_B3);
#pragma unroll
                for (int m = 0; m < LODD; ++m) {
                    o[0][m] = bv[m]; o[1][m] = bv[m];
                    o[2][m] = bv[m]; o[3][m] = bv[m];
                }
            }
#pragma unroll
            for (int j = 0; j < HD; ++j) {
                float wv[6]; LOAD6(wv, wb + OFF_W3 + j * 8);
#pragma unroll
                for (int m = 0; m < LODD; ++m) {
                    o[0][m] = fmaf(h2[0][j], wv[m], o[0][m]);
                    o[1][m] = fmaf(h2[1][j], wv[m], o[1][m]);
                    o[2][m] = fmaf(h2[2][j], wv[m], o[2][m]);
                    o[3][m] = fmaf(h2[3][j], wv[m], o[3][m]);
                }
            }
#pragma unroll
            for (int s = 0; s < 4; ++s)
#pragma unroll
                for (int m = 0; m < LODD; ++m)
                    obuf[(s * 64 + lane) * LSTRIDE + wave * LODD + m] = o[s][m];
        }

        lds_barrier();   // stash visible to all waves

        // ---- flush: 24 (or 12) floats per row x 256 rows ----
        const int rem = NN - (g * 16 + c * 4);
        const int nv  = rem < 4 ? rem : 4;
        if (nv == 4) {
            for (int f = tid; f < 256 * 6; f += 256) {
                const int row  = f / 6;                  // compile-time div
                const int colq = f - row * 6;
                const float* sp = obuf + row * LSTRIDE + colq * 4;
                float4 v = make_float4(sp[0], sp[1], sp[2], sp[3]);
                *(float4*)(out + (size_t)(b0 + row) * ROWF
                           + g * 96 + c * 24 + colq * 4) = v;
            }
        } else {        // tail chunk: nv = 2 -> 3 float4 per row
            for (int f = tid; f < 256 * 3; f += 256) {
                const int row  = f / 3;
                const int colq = f - row * 3;
                const float* sp = obuf + row * LSTRIDE + colq * 4;
                float4 v = make_float4(sp[0], sp[1], sp[2], sp[3]);
                *(float4*)(out + (size_t)(b0 + row) * ROWF
                           + g * 96 + c * 24 + colq * 4) = v;
            }
        }
        lds_barrier();   // flush reads done -> obuf reusable

#pragma unroll
        for (int s = 0; s < 4; ++s) pr[s] = prn[s];
    }
}

extern "C" void kernel_launch(void* const* d_in, const int* in_sizes, int n_in,
                              void* d_out, int out_size, void* d_ws, size_t ws_size,
                              hipStream_t stream) {
    const float* prior  = (const float*)d_in[0];
    const float* camera = (const float*)d_in[1];
    const float* W1     = (const float*)d_in[2];
    const float* b1     = (const float*)d_in[3];
    const float* W2     = (const float*)d_in[4];
    const float* b2     = (const float*)d_in[5];
    const float* W3     = (const float*)d_in[6];
    const float* b3     = (const float*)d_in[7];
    float* out = (float*)d_out;

    dim3 grid(8192 / 256, NG);   // 32 x 46 = 1472 blocks
    dim3 block(256);
    Net_18966575579675_kernel<<<grid, block, 0, stream>>>(
        prior, camera, W1, b1, W2, b2, W3, b3, out);
}